// Round 2
// baseline (307.571 us; speedup 1.0000x reference)
//
#include <hip/hip_runtime.h>

#define DEV __device__ __forceinline__

typedef __bf16 bf16x8 __attribute__((ext_vector_type(8)));
typedef float f32x4 __attribute__((ext_vector_type(4)));

static constexpr int Tn = 2048;
static constexpr int Dn = 1024;
static constexpr int NHn = 32;
static constexpr int Mn = 2 * Tn;  // B*T = 4096
static constexpr float QSCALE = 0.17677669529663687f * 1.4426950408889634f;  // 1/sqrt(32)*log2e

// native RTNE cast: compiler emits v_cvt_pk_bf16_f32 (1 op vs 3 int ops)
DEV unsigned short f2bf(float f) {
    return __builtin_bit_cast(unsigned short, (__bf16)f);
}

#define GPTR(p) ((const __attribute__((address_space(1))) void*)(p))
#define LPTR(p) ((__attribute__((address_space(3))) void*)(p))

// ---------------- single fused cast: x (1M float4) + 4 weights (1M float4) ----------------
__global__ __launch_bounds__(256) void cast_all(
    const float* __restrict__ x, const float* __restrict__ Wq, const float* __restrict__ Wk,
    const float* __restrict__ Wv, const float* __restrict__ Wp,
    unsigned short* __restrict__ xb, unsigned short* __restrict__ wall) {
    int i = blockIdx.x * 256 + threadIdx.x;  // [0, 2M)
    const float* src;
    ushort4* dst;
    if (i < (1 << 20)) {
        src = x + (size_t)i * 4;
        dst = reinterpret_cast<ushort4*>(xb) + i;
    } else {
        int j = i - (1 << 20);
        int sel = j >> 18, off = j & ((1 << 18) - 1);
        const float* w = (sel == 0) ? Wq : (sel == 1) ? Wk : (sel == 2) ? Wv : Wp;
        src = w + (size_t)off * 4;
        dst = reinterpret_cast<ushort4*>(wall) + ((size_t)sel << 18) + off;
    }
    float4 v = *reinterpret_cast<const float4*>(src);
    ushort4 o;
    o.x = f2bf(v.x); o.y = f2bf(v.y); o.z = f2bf(v.z); o.w = f2bf(v.w);
    *dst = o;
}

// ---------------- fused QKV GEMM (m97 pattern) + RMSNorm/RoPE/relayout epilogue ----------------
// z=0: Q -> rms+rope+gain+exp2-scale -> Qn (b,h,t,d)
// z=1: K -> rms+rope              -> Kn (b,h,t,d)
// z=2: V -> transpose store        -> Vt (b,h,d,t)
__global__ __launch_bounds__(256) void gemm_qkv(
    const unsigned short* __restrict__ A, const unsigned short* __restrict__ Wall,
    unsigned short* __restrict__ Qn, unsigned short* __restrict__ Kn, unsigned short* __restrict__ Vt,
    const float* __restrict__ gain, const float* __restrict__ cosp, const float* __restrict__ sinp) {
    const int z = blockIdx.z;
    const unsigned short* Bm = Wall + (size_t)z * (Dn * Dn);
    const int m0 = blockIdx.x * 128, n0 = blockIdx.y * 128;
    const int tid = threadIdx.x, w = tid >> 6, l = tid & 63;
    const int wm = w & 1, wn = w >> 1, lm = l & 15, quad = l >> 4;

    __shared__ __align__(16) unsigned short As[128 * 32];  // lane-linear, no padding (global_load_lds)
    __shared__ __align__(16) unsigned short Bs[128 * 32];

    f32x4 acc[4][4] = {};

    const int r0 = (w * 2 + 0) * 16 + (l >> 2);
    const int r1 = (w * 2 + 1) * 16 + (l >> 2);
    const int c0 = (l & 3) * 8;
    const unsigned short* gA0 = A + (long)(m0 + r0) * Dn + c0;
    const unsigned short* gA1 = A + (long)(m0 + r1) * Dn + c0;
    const unsigned short* gB0 = Bm + (long)(n0 + r0) * Dn + c0;
    const unsigned short* gB1 = Bm + (long)(n0 + r1) * Dn + c0;
    unsigned short* lA0 = As + (w * 2 + 0) * 16 * 32;
    unsigned short* lA1 = As + (w * 2 + 1) * 16 * 32;
    unsigned short* lB0 = Bs + (w * 2 + 0) * 16 * 32;
    unsigned short* lB1 = Bs + (w * 2 + 1) * 16 * 32;

    for (int kk = 0; kk < Dn; kk += 32) {
        __builtin_amdgcn_global_load_lds(GPTR(gA0 + kk), LPTR(lA0), 16, 0, 0);
        __builtin_amdgcn_global_load_lds(GPTR(gA1 + kk), LPTR(lA1), 16, 0, 0);
        __builtin_amdgcn_global_load_lds(GPTR(gB0 + kk), LPTR(lB0), 16, 0, 0);
        __builtin_amdgcn_global_load_lds(GPTR(gB1 + kk), LPTR(lB1), 16, 0, 0);
        __syncthreads();
        bf16x8 af[4], bfv[4];
#pragma unroll
        for (int mt = 0; mt < 4; ++mt)
            af[mt] = __builtin_bit_cast(bf16x8,
                *reinterpret_cast<const uint4*>(As + (wm * 64 + mt * 16 + lm) * 32 + quad * 8));
#pragma unroll
        for (int nt = 0; nt < 4; ++nt)
            bfv[nt] = __builtin_bit_cast(bf16x8,
                *reinterpret_cast<const uint4*>(Bs + (wn * 64 + nt * 16 + lm) * 32 + quad * 8));
#pragma unroll
        for (int mt = 0; mt < 4; ++mt)
#pragma unroll
            for (int nt = 0; nt < 4; ++nt)
                acc[mt][nt] = __builtin_amdgcn_mfma_f32_16x16x32_bf16(af[mt], bfv[nt], acc[mt][nt], 0, 0, 0);
        __syncthreads();
    }

    if (z == 2) {
        // V transpose-store: rows r=0..3 are consecutive t -> ushort4
#pragma unroll
        for (int mt = 0; mt < 4; ++mt) {
            int row0 = m0 + wm * 64 + mt * 16 + quad * 4;
            int b_ = row0 >> 11, t_ = row0 & (Tn - 1);
#pragma unroll
            for (int nt = 0; nt < 4; ++nt) {
                int col = n0 + wn * 64 + nt * 16 + lm;
                int hh = col >> 5, dd = col & 31;
                ushort4 o4;
                o4.x = f2bf(acc[mt][nt][0]); o4.y = f2bf(acc[mt][nt][1]);
                o4.z = f2bf(acc[mt][nt][2]); o4.w = f2bf(acc[mt][nt][3]);
                *reinterpret_cast<ushort4*>(&Vt[((long)(b_ * NHn + hh) * 32 + dd) * Tn + t_]) = o4;
            }
        }
    } else {
        unsigned short* dst = z ? Kn : Qn;
#pragma unroll
        for (int mt = 0; mt < 4; ++mt)
#pragma unroll
            for (int r = 0; r < 4; ++r) {
                int row = m0 + wm * 64 + mt * 16 + quad * 4 + r;
                int b_ = row >> 11, t_ = row & (Tn - 1);
                float c = cosp[t_ * 16 + lm], s = sinp[t_ * 16 + lm];
#pragma unroll
                for (int g = 0; g < 2; ++g) {
                    // head = 32 cols = nt in {2g, 2g+1}; RoPE pair (d, d+16) lives in same lane
                    float x1 = acc[mt][2 * g][r], x2 = acc[mt][2 * g + 1][r];
                    float ssv = x1 * x1 + x2 * x2;
#pragma unroll
                    for (int off = 8; off >= 1; off >>= 1) ssv += __shfl_xor(ssv, off, 16);
                    float rinv = rsqrtf(ssv * (1.0f / 32.0f) + 1e-6f);
                    x1 *= rinv; x2 *= rinv;
                    float o1 = x1 * c - x2 * s;
                    float o2 = x2 * c + x1 * s;
                    int hh = (n0 + wn * 64 + g * 32) >> 5;
                    if (z == 0) { float gs = gain[hh] * QSCALE; o1 *= gs; o2 *= gs; }
                    long base = ((long)(b_ * NHn + hh) * Tn + t_) * 32;
                    dst[base + lm] = f2bf(o1);
                    dst[base + 16 + lm] = f2bf(o2);
                }
            }
    }
}

// ---------------- proj GEMM (m97 pattern), fp32 out ----------------
__global__ __launch_bounds__(256) void gemm_proj(
    const unsigned short* __restrict__ A, const unsigned short* __restrict__ Bm,
    float* __restrict__ C) {
    const int m0 = blockIdx.x * 128, n0 = blockIdx.y * 128;
    const int tid = threadIdx.x, w = tid >> 6, l = tid & 63;
    const int wm = w & 1, wn = w >> 1, lm = l & 15, quad = l >> 4;

    __shared__ __align__(16) unsigned short As[128 * 32];
    __shared__ __align__(16) unsigned short Bs[128 * 32];

    f32x4 acc[4][4] = {};

    const int r0 = (w * 2 + 0) * 16 + (l >> 2);
    const int r1 = (w * 2 + 1) * 16 + (l >> 2);
    const int c0 = (l & 3) * 8;
    const unsigned short* gA0 = A + (long)(m0 + r0) * Dn + c0;
    const unsigned short* gA1 = A + (long)(m0 + r1) * Dn + c0;
    const unsigned short* gB0 = Bm + (long)(n0 + r0) * Dn + c0;
    const unsigned short* gB1 = Bm + (long)(n0 + r1) * Dn + c0;
    unsigned short* lA0 = As + (w * 2 + 0) * 16 * 32;
    unsigned short* lA1 = As + (w * 2 + 1) * 16 * 32;
    unsigned short* lB0 = Bs + (w * 2 + 0) * 16 * 32;
    unsigned short* lB1 = Bs + (w * 2 + 1) * 16 * 32;

    for (int kk = 0; kk < Dn; kk += 32) {
        __builtin_amdgcn_global_load_lds(GPTR(gA0 + kk), LPTR(lA0), 16, 0, 0);
        __builtin_amdgcn_global_load_lds(GPTR(gA1 + kk), LPTR(lA1), 16, 0, 0);
        __builtin_amdgcn_global_load_lds(GPTR(gB0 + kk), LPTR(lB0), 16, 0, 0);
        __builtin_amdgcn_global_load_lds(GPTR(gB1 + kk), LPTR(lB1), 16, 0, 0);
        __syncthreads();
        bf16x8 af[4], bfv[4];
#pragma unroll
        for (int mt = 0; mt < 4; ++mt)
            af[mt] = __builtin_bit_cast(bf16x8,
                *reinterpret_cast<const uint4*>(As + (wm * 64 + mt * 16 + lm) * 32 + quad * 8));
#pragma unroll
        for (int nt = 0; nt < 4; ++nt)
            bfv[nt] = __builtin_bit_cast(bf16x8,
                *reinterpret_cast<const uint4*>(Bs + (wn * 64 + nt * 16 + lm) * 32 + quad * 8));
#pragma unroll
        for (int mt = 0; mt < 4; ++mt)
#pragma unroll
            for (int nt = 0; nt < 4; ++nt)
                acc[mt][nt] = __builtin_amdgcn_mfma_f32_16x16x32_bf16(af[mt], bfv[nt], acc[mt][nt], 0, 0, 0);
        __syncthreads();
    }
#pragma unroll
    for (int mt = 0; mt < 4; ++mt)
#pragma unroll
        for (int nt = 0; nt < 4; ++nt)
#pragma unroll
            for (int r = 0; r < 4; ++r) {
                int rg = m0 + wm * 64 + mt * 16 + quad * 4 + r;
                int cg = n0 + wn * 64 + nt * 16 + lm;
                C[(long)rg * Dn + cg] = acc[mt][nt][r];
            }
}

// ---------------- flash attention: round-0 structure + intra-block k-split ----------------
// 512 threads = 8 waves. Wave (wq, kg): wq = w&3 owns q-rows [q0, q0+32) of the 128-row tile
// (32 rows/wave -> K/V HBM traffic SAME as round-0; the round-1 regression came from halving
// this). kg = w>>2 splits the causal k-range in half; since M is static (from Q only), the two
// halves' (o, l) partials combine LINEARLY via one padded-LDS exchange per pass. Blocks pair
// q-tiles (bx, 15-bx): every wave does 15-17 k-tiles. Grid (8,32,2)=512 blocks x 8 waves =
// 16 waves/CU (2 blocks/CU: LDS 44KB, VGPR<=128) -- 2x round-0 occupancy at equal traffic.
__global__ __launch_bounds__(512, 4) void attn(
    const unsigned short* __restrict__ Qn, const unsigned short* __restrict__ Kn,
    const unsigned short* __restrict__ Vt, unsigned short* __restrict__ Y) {
    const int bx = blockIdx.x, h = blockIdx.y, b = blockIdx.z;
    const int tid = threadIdx.x, w = tid >> 6, l = tid & 63;
    const int wq = w & 3, kg = w >> 2;
    const int lm = l & 15, quad = l >> 4;
    const long bh = b * NHn + h;
    const unsigned short* Qh = Qn + bh * Tn * 32;
    const unsigned short* Kh = Kn + bh * Tn * 32;
    const unsigned short* Vh = Vt + bh * 32 * Tn;
    __shared__ __align__(16) unsigned short Pl[8][16][76];  // per-wave private P staging
    __shared__ float Po[4][64][25];                         // k-half partial exchange (stride 25: conflict-free)
    unsigned short* Pw = &Pl[w][0][0];

    for (int pass = 0; pass < 2; ++pass) {
        const int qb = pass ? (15 - bx) : bx;
        const int q0 = qb * 128 + wq * 32;

        bf16x8 qf[2];
        f32x4 negC[2];  // -M per output row, used as QK^T mfma C-initializer
        float lpart[2][4] = {};
        f32x4 o[2][2] = {{{0.f, 0.f, 0.f, 0.f}, {0.f, 0.f, 0.f, 0.f}},
                         {{0.f, 0.f, 0.f, 0.f}, {0.f, 0.f, 0.f, 0.f}}};
#pragma unroll
        for (int t = 0; t < 2; ++t) {
            qf[t] = __builtin_bit_cast(bf16x8,
                *reinterpret_cast<const uint4*>(Qh + (q0 + t * 16 + lm) * 32 + quad * 8));
            float ss = 0.f;
#pragma unroll
            for (int j = 0; j < 8; ++j) { float v = (float)qf[t][j]; ss += v * v; }
            ss += __shfl_xor(ss, 16);
            ss += __shfl_xor(ss, 32);
            float Mv = __builtin_sqrtf(ss * 32.0f);  // |q_scaled| * |k|max, |k|=sqrt(32) after rms
#pragma unroll
            for (int r = 0; r < 4; ++r) negC[t][r] = -__shfl(Mv, quad * 4 + r, 16);
        }

        // k-tile range for this wave: tiles [ts, te) of size 64
        const int ntiles = (q0 >> 6) + 1;     // causal tiles covering [0, q0+31]
        const int nsplit = ntiles >> 1;
        const int ts = kg ? nsplit : 0;
        const int te = kg ? ntiles : nsplit;

        uint4 ka[4], va[4], kb2[4], vb2[4];

        auto load_t = [&](uint4* kd, uint4* vd, int k0) {
#pragma unroll
            for (int i = 0; i < 4; ++i)
                kd[i] = *reinterpret_cast<const uint4*>(Kh + (k0 + i * 16 + lm) * 32 + quad * 8);
#pragma unroll
            for (int kf2 = 0; kf2 < 2; ++kf2)
#pragma unroll
                for (int nh_ = 0; nh_ < 2; ++nh_)
                    vd[kf2 * 2 + nh_] = *reinterpret_cast<const uint4*>(
                        Vh + (nh_ * 16 + lm) * Tn + k0 + kf2 * 32 + quad * 8);
        };

        auto compute_t = [&](const uint4* kd, const uint4* vd, int k0) {
#pragma unroll
            for (int t = 0; t < 2; ++t) {
                if (k0 > q0 + t * 16 + 15) continue;
                f32x4 s[4];
#pragma unroll
                for (int i = 0; i < 4; ++i)
                    s[i] = __builtin_amdgcn_mfma_f32_16x16x32_bf16(
                        qf[t], __builtin_bit_cast(bf16x8, kd[i]), negC[t], 0, 0, 0);
                const bool full = (k0 + 63) <= (q0 + t * 16);
#pragma unroll
                for (int r = 0; r < 4; ++r) {
                    const int qrow = q0 + t * 16 + quad * 4 + r;
                    float ls = lpart[t][r];
#pragma unroll
                    for (int i = 0; i < 4; ++i) {
                        float p = __builtin_amdgcn_exp2f(s[i][r]);
                        if (!full) {
                            int kc = k0 + i * 16 + lm;
                            p = (kc <= qrow) ? p : 0.0f;
                        }
                        s[i][r] = p;
                        ls += p;
                    }
                    lpart[t][r] = ls;
                }
#pragma unroll
                for (int i = 0; i < 4; ++i)
#pragma unroll
                    for (int r = 0; r < 4; ++r)
                        Pw[(quad * 4 + r) * 76 + i * 16 + lm] = f2bf(s[i][r]);
#pragma unroll
                for (int kf2 = 0; kf2 < 2; ++kf2) {
                    bf16x8 pf = __builtin_bit_cast(bf16x8,
                        *reinterpret_cast<const uint4*>(Pw + lm * 76 + kf2 * 32 + quad * 8));
#pragma unroll
                    for (int nh_ = 0; nh_ < 2; ++nh_)
                        o[t][nh_] = __builtin_amdgcn_mfma_f32_16x16x32_bf16(
                            pf, __builtin_bit_cast(bf16x8, vd[kf2 * 2 + nh_]), o[t][nh_], 0, 0, 0);
                }
            }
        };

        // ping-pong: prefetch next tile's K/V while computing current
        if (te > ts) {
            int k0 = ts * 64;
            const int kendv = (te - 1) * 64;
            load_t(ka, va, k0);
            while (true) {
                int nk = k0 + 64;
                if (nk <= kendv) load_t(kb2, vb2, nk);
                compute_t(ka, va, k0);
                if (nk > kendv) break;
                k0 = nk;
                nk = k0 + 64;
                if (nk <= kendv) load_t(ka, va, nk);
                compute_t(kb2, vb2, k0);
                if (nk > kendv) break;
                k0 = nk;
            }
        }

        // ---- linear partial combine (static M => no max merge needed) ----
        if (kg) {
            float* p = &Po[wq][l][0];
#pragma unroll
            for (int t = 0; t < 2; ++t)
#pragma unroll
                for (int nh_ = 0; nh_ < 2; ++nh_)
#pragma unroll
                    for (int r = 0; r < 4; ++r) p[(t * 2 + nh_) * 4 + r] = o[t][nh_][r];
#pragma unroll
            for (int t = 0; t < 2; ++t)
#pragma unroll
                for (int r = 0; r < 4; ++r) p[16 + t * 4 + r] = lpart[t][r];
        }
        __syncthreads();
        if (!kg) {
            const float* p = &Po[wq][l][0];
#pragma unroll
            for (int t = 0; t < 2; ++t)
#pragma unroll
                for (int r = 0; r < 4; ++r) {
                    float ls = lpart[t][r] + p[16 + t * 4 + r];
#pragma unroll
                    for (int off = 8; off >= 1; off >>= 1) ls += __shfl_xor(ls, off, 16);
                    float inv = 1.0f / ls;
                    int qrow = q0 + t * 16 + quad * 4 + r;
                    long base = ((long)(b * Tn + qrow) * NHn + h) * 32;
                    Y[base + lm] = f2bf((o[t][0][r] + p[(t * 2 + 0) * 4 + r]) * inv);
                    Y[base + 16 + lm] = f2bf((o[t][1][r] + p[(t * 2 + 1) * 4 + r]) * inv);
                }
        }
        __syncthreads();  // protect Po before next pass overwrites
    }
}

extern "C" void kernel_launch(void* const* d_in, const int* in_sizes, int n_in,
                              void* d_out, int out_size, void* d_ws, size_t ws_size,
                              hipStream_t stream) {
    (void)in_sizes; (void)n_in; (void)out_size; (void)ws_size;
    const float* x = (const float*)d_in[0];
    const float* Wq = (const float*)d_in[1];
    const float* Wk = (const float*)d_in[2];
    const float* Wv = (const float*)d_in[3];
    const float* Wp = (const float*)d_in[4];
    const float* gain = (const float*)d_in[5];
    const float* cosp = (const float*)d_in[6];
    const float* sinp = (const float*)d_in[7];

    char* ws = (char*)d_ws;
    const size_t SZ = (size_t)Mn * Dn * 2;  // 8 MB
    unsigned short* xb = (unsigned short*)ws;
    unsigned short* wall = (unsigned short*)(ws + SZ);  // [Wq|Wk|Wv|Wp], 8 MB
    unsigned short* qn = (unsigned short*)(ws + 2 * SZ);
    unsigned short* kn = qn + (size_t)Mn * Dn;
    unsigned short* vt = kn + (size_t)Mn * Dn;
    unsigned short* ybuf = vt + (size_t)Mn * Dn;
    // total ws: 48 MB

    cast_all<<<8192, 256, 0, stream>>>(x, Wq, Wk, Wv, Wp, xb, wall);

    gemm_qkv<<<dim3(Mn / 128, Dn / 128, 3), 256, 0, stream>>>(
        xb, wall, qn, kn, vt, gain, cosp, sinp);

    attn<<<dim3(8, NHn, 2), 512, 0, stream>>>(qn, kn, vt, ybuf);

    gemm_proj<<<dim3(Mn / 128, Dn / 128), 256, 0, stream>>>(
        ybuf, wall + (size_t)3 * Dn * Dn, (float*)d_out);
}

// Round 3
// 233.626 us; speedup vs baseline: 1.3165x; 1.3165x over previous
//
#include <hip/hip_runtime.h>

#define DEV __device__ __forceinline__

typedef __bf16 bf16x8 __attribute__((ext_vector_type(8)));
typedef float f32x4 __attribute__((ext_vector_type(4)));

static constexpr int Tn = 2048;
static constexpr int Dn = 1024;
static constexpr int NHn = 32;
static constexpr int Mn = 2 * Tn;  // B*T = 4096
static constexpr float QSCALE = 0.17677669529663687f * 1.4426950408889634f;  // 1/sqrt(32)*log2e

// native RTNE cast: compiler emits v_cvt_pk_bf16_f32 (1 op vs 3 int ops)
DEV unsigned short f2bf(float f) {
    return __builtin_bit_cast(unsigned short, (__bf16)f);
}

#define GPTR(p) ((const __attribute__((address_space(1))) void*)(p))
#define LPTR(p) ((__attribute__((address_space(3))) void*)(p))

// ---------------- single fused cast: x (1M float4) + 4 weights (1M float4) ----------------
__global__ __launch_bounds__(256) void cast_all(
    const float* __restrict__ x, const float* __restrict__ Wq, const float* __restrict__ Wk,
    const float* __restrict__ Wv, const float* __restrict__ Wp,
    unsigned short* __restrict__ xb, unsigned short* __restrict__ wall) {
    int i = blockIdx.x * 256 + threadIdx.x;  // [0, 2M)
    const float* src;
    ushort4* dst;
    if (i < (1 << 20)) {
        src = x + (size_t)i * 4;
        dst = reinterpret_cast<ushort4*>(xb) + i;
    } else {
        int j = i - (1 << 20);
        int sel = j >> 18, off = j & ((1 << 18) - 1);
        const float* w = (sel == 0) ? Wq : (sel == 1) ? Wk : (sel == 2) ? Wv : Wp;
        src = w + (size_t)off * 4;
        dst = reinterpret_cast<ushort4*>(wall) + ((size_t)sel << 18) + off;
    }
    float4 v = *reinterpret_cast<const float4*>(src);
    ushort4 o;
    o.x = f2bf(v.x); o.y = f2bf(v.y); o.z = f2bf(v.z); o.w = f2bf(v.w);
    *dst = o;
}

// ---------------- fused QKV GEMM (m97 pattern) + RMSNorm/RoPE/relayout epilogue ----------------
// z=0: Q -> rms+rope+gain+exp2-scale -> Qn (b,h,t,d)
// z=1: K -> rms+rope              -> Kn (b,h,t,d)
// z=2: V -> transpose store        -> Vt (b,h,d,t)
__global__ __launch_bounds__(256) void gemm_qkv(
    const unsigned short* __restrict__ A, const unsigned short* __restrict__ Wall,
    unsigned short* __restrict__ Qn, unsigned short* __restrict__ Kn, unsigned short* __restrict__ Vt,
    const float* __restrict__ gain, const float* __restrict__ cosp, const float* __restrict__ sinp) {
    const int z = blockIdx.z;
    const unsigned short* Bm = Wall + (size_t)z * (Dn * Dn);
    const int m0 = blockIdx.x * 128, n0 = blockIdx.y * 128;
    const int tid = threadIdx.x, w = tid >> 6, l = tid & 63;
    const int wm = w & 1, wn = w >> 1, lm = l & 15, quad = l >> 4;

    __shared__ __align__(16) unsigned short As[128 * 32];  // lane-linear, no padding (global_load_lds)
    __shared__ __align__(16) unsigned short Bs[128 * 32];

    f32x4 acc[4][4] = {};

    const int r0 = (w * 2 + 0) * 16 + (l >> 2);
    const int r1 = (w * 2 + 1) * 16 + (l >> 2);
    const int c0 = (l & 3) * 8;
    const unsigned short* gA0 = A + (long)(m0 + r0) * Dn + c0;
    const unsigned short* gA1 = A + (long)(m0 + r1) * Dn + c0;
    const unsigned short* gB0 = Bm + (long)(n0 + r0) * Dn + c0;
    const unsigned short* gB1 = Bm + (long)(n0 + r1) * Dn + c0;
    unsigned short* lA0 = As + (w * 2 + 0) * 16 * 32;
    unsigned short* lA1 = As + (w * 2 + 1) * 16 * 32;
    unsigned short* lB0 = Bs + (w * 2 + 0) * 16 * 32;
    unsigned short* lB1 = Bs + (w * 2 + 1) * 16 * 32;

    for (int kk = 0; kk < Dn; kk += 32) {
        __builtin_amdgcn_global_load_lds(GPTR(gA0 + kk), LPTR(lA0), 16, 0, 0);
        __builtin_amdgcn_global_load_lds(GPTR(gA1 + kk), LPTR(lA1), 16, 0, 0);
        __builtin_amdgcn_global_load_lds(GPTR(gB0 + kk), LPTR(lB0), 16, 0, 0);
        __builtin_amdgcn_global_load_lds(GPTR(gB1 + kk), LPTR(lB1), 16, 0, 0);
        __syncthreads();
        bf16x8 af[4], bfv[4];
#pragma unroll
        for (int mt = 0; mt < 4; ++mt)
            af[mt] = __builtin_bit_cast(bf16x8,
                *reinterpret_cast<const uint4*>(As + (wm * 64 + mt * 16 + lm) * 32 + quad * 8));
#pragma unroll
        for (int nt = 0; nt < 4; ++nt)
            bfv[nt] = __builtin_bit_cast(bf16x8,
                *reinterpret_cast<const uint4*>(Bs + (wn * 64 + nt * 16 + lm) * 32 + quad * 8));
#pragma unroll
        for (int mt = 0; mt < 4; ++mt)
#pragma unroll
            for (int nt = 0; nt < 4; ++nt)
                acc[mt][nt] = __builtin_amdgcn_mfma_f32_16x16x32_bf16(af[mt], bfv[nt], acc[mt][nt], 0, 0, 0);
        __syncthreads();
    }

    if (z == 2) {
        // V transpose-store: rows r=0..3 are consecutive t -> ushort4
#pragma unroll
        for (int mt = 0; mt < 4; ++mt) {
            int row0 = m0 + wm * 64 + mt * 16 + quad * 4;
            int b_ = row0 >> 11, t_ = row0 & (Tn - 1);
#pragma unroll
            for (int nt = 0; nt < 4; ++nt) {
                int col = n0 + wn * 64 + nt * 16 + lm;
                int hh = col >> 5, dd = col & 31;
                ushort4 o4;
                o4.x = f2bf(acc[mt][nt][0]); o4.y = f2bf(acc[mt][nt][1]);
                o4.z = f2bf(acc[mt][nt][2]); o4.w = f2bf(acc[mt][nt][3]);
                *reinterpret_cast<ushort4*>(&Vt[((long)(b_ * NHn + hh) * 32 + dd) * Tn + t_]) = o4;
            }
        }
    } else {
        unsigned short* dst = z ? Kn : Qn;
#pragma unroll
        for (int mt = 0; mt < 4; ++mt)
#pragma unroll
            for (int r = 0; r < 4; ++r) {
                int row = m0 + wm * 64 + mt * 16 + quad * 4 + r;
                int b_ = row >> 11, t_ = row & (Tn - 1);
                float c = cosp[t_ * 16 + lm], s = sinp[t_ * 16 + lm];
#pragma unroll
                for (int g = 0; g < 2; ++g) {
                    // head = 32 cols = nt in {2g, 2g+1}; RoPE pair (d, d+16) lives in same lane
                    float x1 = acc[mt][2 * g][r], x2 = acc[mt][2 * g + 1][r];
                    float ssv = x1 * x1 + x2 * x2;
#pragma unroll
                    for (int off = 8; off >= 1; off >>= 1) ssv += __shfl_xor(ssv, off, 16);
                    float rinv = rsqrtf(ssv * (1.0f / 32.0f) + 1e-6f);
                    x1 *= rinv; x2 *= rinv;
                    float o1 = x1 * c - x2 * s;
                    float o2 = x2 * c + x1 * s;
                    int hh = (n0 + wn * 64 + g * 32) >> 5;
                    if (z == 0) { float gs = gain[hh] * QSCALE; o1 *= gs; o2 *= gs; }
                    long base = ((long)(b_ * NHn + hh) * Tn + t_) * 32;
                    dst[base + lm] = f2bf(o1);
                    dst[base + 16 + lm] = f2bf(o2);
                }
            }
    }
}

// ---------------- proj GEMM (m97 pattern), fp32 out ----------------
__global__ __launch_bounds__(256) void gemm_proj(
    const unsigned short* __restrict__ A, const unsigned short* __restrict__ Bm,
    float* __restrict__ C) {
    const int m0 = blockIdx.x * 128, n0 = blockIdx.y * 128;
    const int tid = threadIdx.x, w = tid >> 6, l = tid & 63;
    const int wm = w & 1, wn = w >> 1, lm = l & 15, quad = l >> 4;

    __shared__ __align__(16) unsigned short As[128 * 32];
    __shared__ __align__(16) unsigned short Bs[128 * 32];

    f32x4 acc[4][4] = {};

    const int r0 = (w * 2 + 0) * 16 + (l >> 2);
    const int r1 = (w * 2 + 1) * 16 + (l >> 2);
    const int c0 = (l & 3) * 8;
    const unsigned short* gA0 = A + (long)(m0 + r0) * Dn + c0;
    const unsigned short* gA1 = A + (long)(m0 + r1) * Dn + c0;
    const unsigned short* gB0 = Bm + (long)(n0 + r0) * Dn + c0;
    const unsigned short* gB1 = Bm + (long)(n0 + r1) * Dn + c0;
    unsigned short* lA0 = As + (w * 2 + 0) * 16 * 32;
    unsigned short* lA1 = As + (w * 2 + 1) * 16 * 32;
    unsigned short* lB0 = Bs + (w * 2 + 0) * 16 * 32;
    unsigned short* lB1 = Bs + (w * 2 + 1) * 16 * 32;

    for (int kk = 0; kk < Dn; kk += 32) {
        __builtin_amdgcn_global_load_lds(GPTR(gA0 + kk), LPTR(lA0), 16, 0, 0);
        __builtin_amdgcn_global_load_lds(GPTR(gA1 + kk), LPTR(lA1), 16, 0, 0);
        __builtin_amdgcn_global_load_lds(GPTR(gB0 + kk), LPTR(lB0), 16, 0, 0);
        __builtin_amdgcn_global_load_lds(GPTR(gB1 + kk), LPTR(lB1), 16, 0, 0);
        __syncthreads();
        bf16x8 af[4], bfv[4];
#pragma unroll
        for (int mt = 0; mt < 4; ++mt)
            af[mt] = __builtin_bit_cast(bf16x8,
                *reinterpret_cast<const uint4*>(As + (wm * 64 + mt * 16 + lm) * 32 + quad * 8));
#pragma unroll
        for (int nt = 0; nt < 4; ++nt)
            bfv[nt] = __builtin_bit_cast(bf16x8,
                *reinterpret_cast<const uint4*>(Bs + (wn * 64 + nt * 16 + lm) * 32 + quad * 8));
#pragma unroll
        for (int mt = 0; mt < 4; ++mt)
#pragma unroll
            for (int nt = 0; nt < 4; ++nt)
                acc[mt][nt] = __builtin_amdgcn_mfma_f32_16x16x32_bf16(af[mt], bfv[nt], acc[mt][nt], 0, 0, 0);
        __syncthreads();
    }
#pragma unroll
    for (int mt = 0; mt < 4; ++mt)
#pragma unroll
        for (int nt = 0; nt < 4; ++nt)
#pragma unroll
            for (int r = 0; r < 4; ++r) {
                int rg = m0 + wm * 64 + mt * 16 + quad * 4 + r;
                int cg = n0 + wn * 64 + nt * 16 + lm;
                C[(long)rg * Dn + cg] = acc[mt][nt][r];
            }
}

// ---------------- flash attention: intra-block k-split, NO forced VGPR cap ----------------
// 512 threads = 8 waves. Wave (wq, kg): wq = w&3 owns q-rows [q0, q0+32) (32 rows/wave keeps
// K/V HBM traffic at the round-0 level); kg = w>>2 splits the causal k-range in half. M is
// static (from Q only) so the two halves' (o, l) partials combine LINEARLY via one padded-LDS
// exchange per pass. Blocks pair q-tiles (bx, 15-bx) for balance. Grid (8,32,2) = 512 blocks
// x 8 waves = 16 waves/CU at <=128 VGPR.
// CRITICAL: plain __launch_bounds__(512) -- round 2's (512,4) forced VGPR=64 and spilled the
// ping-pong K/V staging to scratch (222 MB HBM writes). Register floor here is ~116 VGPR.
__global__ __launch_bounds__(512) void attn(
    const unsigned short* __restrict__ Qn, const unsigned short* __restrict__ Kn,
    const unsigned short* __restrict__ Vt, unsigned short* __restrict__ Y) {
    const int bx = blockIdx.x, h = blockIdx.y, b = blockIdx.z;
    const int tid = threadIdx.x, w = tid >> 6, l = tid & 63;
    const int wq = w & 3, kg = w >> 2;
    const int lm = l & 15, quad = l >> 4;
    const long bh = b * NHn + h;
    const unsigned short* Qh = Qn + bh * Tn * 32;
    const unsigned short* Kh = Kn + bh * Tn * 32;
    const unsigned short* Vh = Vt + bh * 32 * Tn;
    __shared__ __align__(16) unsigned short Pl[8][16][76];  // per-wave private P staging
    __shared__ float Po[4][64][25];                         // k-half partial exchange (stride 25: conflict-free)
    unsigned short* Pw = &Pl[w][0][0];

    for (int pass = 0; pass < 2; ++pass) {
        const int qb = pass ? (15 - bx) : bx;
        const int q0 = qb * 128 + wq * 32;

        bf16x8 qf[2];
        f32x4 negC[2];  // -M per output row, used as QK^T mfma C-initializer
        float lpart[2][4] = {};
        f32x4 o[2][2] = {{{0.f, 0.f, 0.f, 0.f}, {0.f, 0.f, 0.f, 0.f}},
                         {{0.f, 0.f, 0.f, 0.f}, {0.f, 0.f, 0.f, 0.f}}};
#pragma unroll
        for (int t = 0; t < 2; ++t) {
            qf[t] = __builtin_bit_cast(bf16x8,
                *reinterpret_cast<const uint4*>(Qh + (q0 + t * 16 + lm) * 32 + quad * 8));
            float ss = 0.f;
#pragma unroll
            for (int j = 0; j < 8; ++j) { float v = (float)qf[t][j]; ss += v * v; }
            ss += __shfl_xor(ss, 16);
            ss += __shfl_xor(ss, 32);
            float Mv = __builtin_sqrtf(ss * 32.0f);  // |q_scaled| * |k|max, |k|=sqrt(32) after rms
#pragma unroll
            for (int r = 0; r < 4; ++r) negC[t][r] = -__shfl(Mv, quad * 4 + r, 16);
        }

        // k-tile range for this wave: tiles [ts, te) of size 64
        const int ntiles = (q0 >> 6) + 1;     // causal tiles covering [0, q0+31]
        const int nsplit = ntiles >> 1;
        const int ts = kg ? nsplit : 0;
        const int te = kg ? ntiles : nsplit;

        uint4 ka[4], va[4], kb2[4], vb2[4];

        auto load_t = [&](uint4* kd, uint4* vd, int k0) {
#pragma unroll
            for (int i = 0; i < 4; ++i)
                kd[i] = *reinterpret_cast<const uint4*>(Kh + (k0 + i * 16 + lm) * 32 + quad * 8);
#pragma unroll
            for (int kf2 = 0; kf2 < 2; ++kf2)
#pragma unroll
                for (int nh_ = 0; nh_ < 2; ++nh_)
                    vd[kf2 * 2 + nh_] = *reinterpret_cast<const uint4*>(
                        Vh + (nh_ * 16 + lm) * Tn + k0 + kf2 * 32 + quad * 8);
        };

        auto compute_t = [&](const uint4* kd, const uint4* vd, int k0) {
#pragma unroll
            for (int t = 0; t < 2; ++t) {
                if (k0 > q0 + t * 16 + 15) continue;
                f32x4 s[4];
#pragma unroll
                for (int i = 0; i < 4; ++i)
                    s[i] = __builtin_amdgcn_mfma_f32_16x16x32_bf16(
                        qf[t], __builtin_bit_cast(bf16x8, kd[i]), negC[t], 0, 0, 0);
                const bool full = (k0 + 63) <= (q0 + t * 16);
#pragma unroll
                for (int r = 0; r < 4; ++r) {
                    const int qrow = q0 + t * 16 + quad * 4 + r;
                    float ls = lpart[t][r];
#pragma unroll
                    for (int i = 0; i < 4; ++i) {
                        float p = __builtin_amdgcn_exp2f(s[i][r]);
                        if (!full) {
                            int kc = k0 + i * 16 + lm;
                            p = (kc <= qrow) ? p : 0.0f;
                        }
                        s[i][r] = p;
                        ls += p;
                    }
                    lpart[t][r] = ls;
                }
#pragma unroll
                for (int i = 0; i < 4; ++i)
#pragma unroll
                    for (int r = 0; r < 4; ++r)
                        Pw[(quad * 4 + r) * 76 + i * 16 + lm] = f2bf(s[i][r]);
#pragma unroll
                for (int kf2 = 0; kf2 < 2; ++kf2) {
                    bf16x8 pf = __builtin_bit_cast(bf16x8,
                        *reinterpret_cast<const uint4*>(Pw + lm * 76 + kf2 * 32 + quad * 8));
#pragma unroll
                    for (int nh_ = 0; nh_ < 2; ++nh_)
                        o[t][nh_] = __builtin_amdgcn_mfma_f32_16x16x32_bf16(
                            pf, __builtin_bit_cast(bf16x8, vd[kf2 * 2 + nh_]), o[t][nh_], 0, 0, 0);
                }
            }
        };

        // ping-pong: prefetch next tile's K/V while computing current
        if (te > ts) {
            int k0 = ts * 64;
            const int kendv = (te - 1) * 64;
            load_t(ka, va, k0);
            while (true) {
                int nk = k0 + 64;
                if (nk <= kendv) load_t(kb2, vb2, nk);
                compute_t(ka, va, k0);
                if (nk > kendv) break;
                k0 = nk;
                nk = k0 + 64;
                if (nk <= kendv) load_t(ka, va, nk);
                compute_t(kb2, vb2, k0);
                if (nk > kendv) break;
                k0 = nk;
            }
        }

        // ---- linear partial combine (static M => no max merge needed) ----
        if (kg) {
            float* p = &Po[wq][l][0];
#pragma unroll
            for (int t = 0; t < 2; ++t)
#pragma unroll
                for (int nh_ = 0; nh_ < 2; ++nh_)
#pragma unroll
                    for (int r = 0; r < 4; ++r) p[(t * 2 + nh_) * 4 + r] = o[t][nh_][r];
#pragma unroll
            for (int t = 0; t < 2; ++t)
#pragma unroll
                for (int r = 0; r < 4; ++r) p[16 + t * 4 + r] = lpart[t][r];
        }
        __syncthreads();
        if (!kg) {
            const float* p = &Po[wq][l][0];
#pragma unroll
            for (int t = 0; t < 2; ++t)
#pragma unroll
                for (int r = 0; r < 4; ++r) {
                    float ls = lpart[t][r] + p[16 + t * 4 + r];
#pragma unroll
                    for (int off = 8; off >= 1; off >>= 1) ls += __shfl_xor(ls, off, 16);
                    float inv = 1.0f / ls;
                    int qrow = q0 + t * 16 + quad * 4 + r;
                    long base = ((long)(b * Tn + qrow) * NHn + h) * 32;
                    Y[base + lm] = f2bf((o[t][0][r] + p[(t * 2 + 0) * 4 + r]) * inv);
                    Y[base + 16 + lm] = f2bf((o[t][1][r] + p[(t * 2 + 1) * 4 + r]) * inv);
                }
        }
        __syncthreads();  // protect Po before next pass overwrites
    }
}

extern "C" void kernel_launch(void* const* d_in, const int* in_sizes, int n_in,
                              void* d_out, int out_size, void* d_ws, size_t ws_size,
                              hipStream_t stream) {
    (void)in_sizes; (void)n_in; (void)out_size; (void)ws_size;
    const float* x = (const float*)d_in[0];
    const float* Wq = (const float*)d_in[1];
    const float* Wk = (const float*)d_in[2];
    const float* Wv = (const float*)d_in[3];
    const float* Wp = (const float*)d_in[4];
    const float* gain = (const float*)d_in[5];
    const float* cosp = (const float*)d_in[6];
    const float* sinp = (const float*)d_in[7];

    char* ws = (char*)d_ws;
    const size_t SZ = (size_t)Mn * Dn * 2;  // 8 MB
    unsigned short* xb = (unsigned short*)ws;
    unsigned short* wall = (unsigned short*)(ws + SZ);  // [Wq|Wk|Wv|Wp], 8 MB
    unsigned short* qn = (unsigned short*)(ws + 2 * SZ);
    unsigned short* kn = qn + (size_t)Mn * Dn;
    unsigned short* vt = kn + (size_t)Mn * Dn;
    unsigned short* ybuf = vt + (size_t)Mn * Dn;
    // total ws: 48 MB

    cast_all<<<8192, 256, 0, stream>>>(x, Wq, Wk, Wv, Wp, xb, wall);

    gemm_qkv<<<dim3(Mn / 128, Dn / 128, 3), 256, 0, stream>>>(
        xb, wall, qn, kn, vt, gain, cosp, sinp);

    attn<<<dim3(8, NHn, 2), 512, 0, stream>>>(qn, kn, vt, ybuf);

    gemm_proj<<<dim3(Mn / 128, Dn / 128), 256, 0, stream>>>(
        ybuf, wall + (size_t)3 * Dn * Dn, (float*)d_out);
}